// Round 9
// baseline (149.922 us; speedup 1.0000x reference)
//
#include <hip/hip_runtime.h>

#define GH 2048
#define GW 2048
#define OH 2046
#define OW 2046

constexpr int R       = 11;               // output rows per band (reads R+2 = 13 rows)
constexpr int BANDS   = 186;              // R * BANDS = 2046
constexpr int CTILES  = 33;               // 62 output cols per tile; 33*62 = 2046
constexpr int NWAVES  = CTILES * BANDS;   // 6138 wave-tasks -> 24 waves/CU
constexpr int NBLOCKS = (NWAVES + 3) / 4; // 1535 blocks
constexpr int PF      = 3;                // prefetch depth (rows in flight per wave)

// workspace layout: partials[NBLOCKS] (8B each), then 4B ticket counter
constexpr size_t COUNTER_OFF = ((size_t)NBLOCKS * 8 + 63) & ~(size_t)63;

// 12-byte packed strain record: one global_load_dwordx3 per lane per row.
struct __align__(4) F3 { float x, y, z; };
typedef unsigned long long u64;
union PU { float2 f; u64 u; };

// Single kernel: stencil + last-block finalize (threadFenceReduction pattern).
// Partials published with agent-scope atomic stores (coherence point = L3,
// bypasses non-coherent per-XCD L2s); ticket fetch_add acq_rel agent-scope.
// No cooperative launch -> graph-capture safe (round-6 failure mode avoided).
__global__ __launch_bounds__(256)
void fused_kernel(const float* __restrict__ E, const float* __restrict__ v,
                  const float* __restrict__ strain, u64* __restrict__ partials,
                  unsigned* __restrict__ counter, float* __restrict__ out) {
    const int wslot = threadIdx.x >> 6;
    const int wid   = blockIdx.x * 4 + wslot;
    const int lane  = threadIdx.x & 63;

    float acc = 0.f, eacc = 0.f;

    if (wid < NWAVES) {                     // inactive waves still reach barriers below
        const int band = wid % BANDS;       // band-major: stacked bands share halo rows on one CU
        const int tile = wid / BANDS;
        const int col  = tile * 62 + lane;  // max = 32*62+63 = 2047: in bounds
        const int row0 = band * R;          // reads rows row0 .. row0+R+1 (max 2047)

        // exactly-once ownership for the E-mean over the full 2048^2 grid
        const bool eown_col = (lane < 62) || (tile == CTILES - 1);
        const int  own_rows = (band == BANDS - 1) ? R + 2 : R;
        const bool out_ok   = (lane < 62);

        // rolling 3-row state
        float he0=0,he1=0,he2=0;
        float hxx0=0,hxx1=0,hxx2=0;
        float hxy0=0,hxy1=0,hxy2=0;
        float dxy0=0,dxy1=0,dxy2=0;
        float dyy0=0,dyy1=0,dyy2=0;

        // depth-PF prefetch buffers (register-resident after full unroll)
        float eb[PF], vb[PF];
        F3    sb[PF];
        int idx = row0 * GW + col;
        #pragma unroll
        for (int p = 0; p < PF; ++p) {
            const int j = idx + p * GW;
            eb[p] = E[j];
            vb[p] = v[j];
            sb[p] = *reinterpret_cast<const F3*>(strain + 3 * (size_t)j);
        }

        #pragma unroll
        for (int k = 0; k < R + 2; ++k) {
            const int s = k % PF;           // static after full unroll (no scratch)
            const float e   = eb[s];
            const float vv  = vb[s];
            const float exx = sb[s].x;
            const float eyy = sb[s].y;
            const float exy = sb[s].z;
            if (k + PF < R + 2) {           // prefetch row k+PF into the freed slot
                const int j = idx + PF * GW;
                eb[s] = E[j];
                vb[s] = v[j];
                sb[s] = *reinterpret_cast<const F3*>(strain + 3 * (size_t)j);
            }
            idx += GW;

            if (eown_col && k < own_rows) eacc += e;

            const float frac = e / (1.f - vv * vv);
            const float sx  = (exx + vv * eyy) * frac;
            const float sy_ = (vv * exx + eyy) * frac;
            const float sz_ = exy * (1.f - vv) * 0.5f * frac;

            const float e1 = __shfl_down(e,   1, 64), e2 = __shfl_down(e,   2, 64);
            const float x1 = __shfl_down(sx,  1, 64), x2 = __shfl_down(sx,  2, 64);
            const float z1 = __shfl_down(sz_, 1, 64), z2 = __shfl_down(sz_, 2, 64);
            const float y2 = __shfl_down(sy_, 2, 64);

            he0=he1;   he1=he2;   he2  = e   + e1 + e2;
            hxx0=hxx1; hxx1=hxx2; hxx2 = sx  + x1 + x2;
            hxy0=hxy1; hxy1=hxy2; hxy2 = sz_ + z1 + z2;
            dxy0=dxy1; dxy1=dxy2; dxy2 = sz_ - z2;
            dyy0=dyy1; dyy1=dyy2; dyy2 = sy_ - y2;

            if (k >= 2) {                   // emit output row (row0 + k - 2)
                const float fx = (hxx2 - hxx0) + (dxy0 + dxy1 + dxy2);
                const float fy = (dyy0 + dyy1 + dyy2) + (hxy2 - hxy0);
                const float inv = 1.f / (he0 + he1 + he2);
                const float c = fabsf(fx * inv) + fabsf(fy * inv);
                acc += out_ok ? c : 0.f;
            }
        }
    }

    // intra-wave reduction
    #pragma unroll
    for (int off = 32; off > 0; off >>= 1) {
        acc  += __shfl_down(acc,  off, 64);
        eacc += __shfl_down(eacc, off, 64);
    }
    __shared__ float sred[4][2];
    __shared__ bool  is_last;
    if (lane == 0) { sred[wslot][0] = acc; sred[wslot][1] = eacc; }
    __syncthreads();
    if (threadIdx.x == 0) {
        PU p;
        p.f = make_float2(sred[0][0] + sred[1][0] + sred[2][0] + sred[3][0],
                          sred[0][1] + sred[1][1] + sred[2][1] + sred[3][1]);
        // publish partial at agent scope (L3 coherence point, skips per-XCD L2)
        __hip_atomic_store(&partials[blockIdx.x], p.u,
                           __ATOMIC_RELAXED, __HIP_MEMORY_SCOPE_AGENT);
        // release orders the partial store before the increment; the block that
        // sees old == NBLOCKS-1 (acquire) therefore sees all 1535 partials.
        unsigned old = __hip_atomic_fetch_add(counter, 1u,
                           __ATOMIC_ACQ_REL, __HIP_MEMORY_SCOPE_AGENT);
        is_last = (old == NBLOCKS - 1);
    }
    __syncthreads();

    if (is_last) {
        __shared__ double sacc[4][2];
        double a = 0.0, e = 0.0;
        for (int i = threadIdx.x; i < NBLOCKS; i += 256) {   // 6 iterations
            PU p;
            p.u = __hip_atomic_load(&partials[i],
                                    __ATOMIC_RELAXED, __HIP_MEMORY_SCOPE_AGENT);
            a += (double)p.f.x;
            e += (double)p.f.y;
        }
        #pragma unroll
        for (int off = 32; off > 0; off >>= 1) {
            a += __shfl_down(a, off, 64);
            e += __shfl_down(e, off, 64);
        }
        if (lane == 0) { sacc[wslot][0] = a; sacc[wslot][1] = e; }
        __syncthreads();
        if (threadIdx.x == 0) {
            double A    = sacc[0][0] + sacc[1][0] + sacc[2][0] + sacc[3][0];
            double Esum = sacc[0][1] + sacc[1][1] + sacc[2][1] + sacc[3][1];
            double M = (double)OH * (double)OW;
            double loss_xy = A / M;
            double loss_e  = fabs(Esum / ((double)GH * (double)GW) - 1.0) / 100.0;
            out[0] = (float)(loss_xy + loss_e);
        }
    }
}

extern "C" void kernel_launch(void* const* d_in, const int* in_sizes, int n_in,
                              void* d_out, int out_size, void* d_ws, size_t ws_size,
                              hipStream_t stream) {
    const float* E      = (const float*)d_in[0];
    const float* v      = (const float*)d_in[1];
    const float* strain = (const float*)d_in[2];
    float* out = (float*)d_out;
    u64* partials = (u64*)d_ws;
    unsigned* counter = (unsigned*)((char*)d_ws + COUNTER_OFF);

    // zero the ticket counter (workspace is re-poisoned before every iteration);
    // stream-ordered + graph-capturable
    hipMemsetAsync(counter, 0, sizeof(unsigned), stream);
    hipLaunchKernelGGL(fused_kernel, dim3(NBLOCKS), dim3(256), 0, stream,
                       E, v, strain, partials, counter, out);
}

// Round 11
// 111.507 us; speedup vs baseline: 1.3445x; 1.3445x over previous
//
#include <hip/hip_runtime.h>

#define GH 2048
#define GW 2048
#define OH 2046
#define OW 2046

constexpr int R      = 11;              // output rows per band (reads R+2 rows)
constexpr int BANDS  = 186;             // R * BANDS = 2046
constexpr int CTILES = 33;              // 62 output cols per tile; 33*62 = 2046
constexpr int NWAVES = CTILES * BANDS;  // 6138 wave-tasks -> ~24 waves/CU
constexpr int NBLOCKS = (NWAVES + 3) / 4;

__global__ __launch_bounds__(256)
void stencil_kernel(const float* __restrict__ E, const float* __restrict__ v,
                    const float* __restrict__ strain, float2* __restrict__ partials) {
    const int wid  = blockIdx.x * 4 + (threadIdx.x >> 6);
    const int lane = threadIdx.x & 63;
    if (wid >= NWAVES) return;                  // wave-uniform exit
    const int tile = wid % CTILES;
    const int band = wid / CTILES;
    const int col  = tile * 62 + lane;          // max = 32*62+63 = 2047: always in bounds
    const int row0 = band * R;                  // reads rows row0 .. row0+R+1 (max 2047)

    // exactly-once ownership for the E-mean over the full 2048^2 grid
    const bool eown_col = (lane < 62) || (tile == CTILES - 1);
    const int  own_rows = (band == BANDS - 1) ? R + 2 : R;
    const bool out_ok   = (lane < 62);

    float he0=0, he1=0, he2=0, hxx0=0, hxx1=0, hxx2=0, hxy0=0, hxy1=0, hxy2=0;
    float sz0=0, sz1=0, sz2=0, sy0=0, sy1=0, sy2=0;
    float acc = 0.f, eacc = 0.f;

    int idx = row0 * GW + col;
    // prefetch row 0
    float e_n  = E[idx];
    float v_n  = v[idx];
    float xx_n = strain[3 * idx + 0];
    float yy_n = strain[3 * idx + 1];
    float xy_n = strain[3 * idx + 2];

    for (int k = 0; k < R + 2; ++k) {
        const float e = e_n, vv = v_n, exx = xx_n, eyy = yy_n, exy = xy_n;
        if (k < R + 1) {                        // prefetch next row while computing this one
            const int idx2 = idx + GW;
            e_n  = E[idx2];
            v_n  = v[idx2];
            xx_n = strain[3 * idx2 + 0];
            yy_n = strain[3 * idx2 + 1];
            xy_n = strain[3 * idx2 + 2];
        }
        if (eown_col && k < own_rows) eacc += e;

        const float frac = e / (1.f - vv * vv);
        const float sx  = (exx + vv * eyy) * frac;
        const float sy_ = (vv * exx + eyy) * frac;
        const float sz_ = exy * (1.f - vv) * 0.5f * frac;

        const float he_  = e   + __shfl_down(e,   1, 64) + __shfl_down(e,   2, 64);
        const float hxx_ = sx  + __shfl_down(sx,  1, 64) + __shfl_down(sx,  2, 64);
        const float hxy_ = sz_ + __shfl_down(sz_, 1, 64) + __shfl_down(sz_, 2, 64);

        he0 = he1;   he1 = he2;   he2 = he_;
        hxx0 = hxx1; hxx1 = hxx2; hxx2 = hxx_;
        hxy0 = hxy1; hxy1 = hxy2; hxy2 = hxy_;
        sz0 = sz1;   sz1 = sz2;   sz2 = sz_;
        sy0 = sy1;   sy1 = sy2;   sy2 = sy_;

        if (k >= 2) {                           // emit output row (row0 + k - 2)
            const float Vxy = sz0 + sz1 + sz2;
            const float Vyy = sy0 + sy1 + sy2;
            const float fx = (hxx2 - hxx0) + Vxy - __shfl_down(Vxy, 2, 64);
            const float fy = (Vyy - __shfl_down(Vyy, 2, 64)) + (hxy2 - hxy0);
            const float Ec = he0 + he1 + he2;
            const float inv = 1.f / Ec;
            const float c = fabsf(fx * inv) + fabsf(fy * inv);
            acc += out_ok ? c : 0.f;
        }
        idx += GW;
    }

    // intra-wave reduction, one plain store per wave
    #pragma unroll
    for (int off = 32; off > 0; off >>= 1) {
        acc  += __shfl_down(acc,  off, 64);
        eacc += __shfl_down(eacc, off, 64);
    }
    if (lane == 0) partials[wid] = make_float2(acc, eacc);
}

__global__ __launch_bounds__(256)
void finalize_kernel(const float2* __restrict__ partials, float* __restrict__ out) {
    __shared__ double sacc[4][2];
    double a = 0.0, e = 0.0;
    for (int i = threadIdx.x; i < NWAVES; i += 256) {
        float2 p = partials[i];
        a += (double)p.x;
        e += (double)p.y;
    }
    #pragma unroll
    for (int off = 32; off > 0; off >>= 1) {
        a += __shfl_down(a, off, 64);
        e += __shfl_down(e, off, 64);
    }
    const int wave = threadIdx.x >> 6;
    if ((threadIdx.x & 63) == 0) { sacc[wave][0] = a; sacc[wave][1] = e; }
    __syncthreads();
    if (threadIdx.x == 0) {
        double A    = sacc[0][0] + sacc[1][0] + sacc[2][0] + sacc[3][0];
        double Esum = sacc[0][1] + sacc[1][1] + sacc[2][1] + sacc[3][1];
        double M = (double)OH * (double)OW;
        double loss_xy = A / M;
        double loss_e  = fabs(Esum / ((double)GH * (double)GW) - 1.0) / 100.0;
        out[0] = (float)(loss_xy + loss_e);
    }
}

extern "C" void kernel_launch(void* const* d_in, const int* in_sizes, int n_in,
                              void* d_out, int out_size, void* d_ws, size_t ws_size,
                              hipStream_t stream) {
    const float* E      = (const float*)d_in[0];
    const float* v      = (const float*)d_in[1];
    const float* strain = (const float*)d_in[2];
    float* out = (float*)d_out;
    float2* partials = (float2*)d_ws;

    hipLaunchKernelGGL(stencil_kernel, dim3(NBLOCKS), dim3(256), 0, stream,
                       E, v, strain, partials);
    hipLaunchKernelGGL(finalize_kernel, dim3(1), dim3(256), 0, stream, partials, out);
}